// Round 1
// baseline (2251.860 us; speedup 1.0000x reference)
//
#include <hip/hip_runtime.h>

#define N_NODES 100000
#define N_EDGES 800000
#define HID 64
#define NGRAPH 64
#define OUTC 2
#define BN_EPS 1e-5f

// ---------------------------------------------------------------------------
// GEMM: Y[n,64] = X[n,64] @ W[64,64] (+ bias) (optionally row-scaled by dinv)
// 256 threads, 64-row tile, 4x4 register micro-tile per thread.
// ---------------------------------------------------------------------------
template <bool ADD_BIAS, bool ROW_SCALE>
__global__ __launch_bounds__(256) void k_gemm(const float* __restrict__ X,
                                              const float* __restrict__ W,
                                              const float* __restrict__ bias,
                                              const float* __restrict__ dinv,
                                              float* __restrict__ Y, int n) {
    __shared__ float sW[64][64];   // [k][c], rows 16B aligned for float4 reads
    __shared__ float sX[64][66];   // pad 2 -> bank spread for 4-row reads
    const int tid  = threadIdx.x;
    const int row0 = blockIdx.x * 64;

    {   // load W (4096 floats) via float4
        const float4* Wv  = reinterpret_cast<const float4*>(W);
        float4*       sWv = reinterpret_cast<float4*>(&sW[0][0]);
        #pragma unroll
        for (int i = tid; i < 1024; i += 256) sWv[i] = Wv[i];
    }
    // load X tile (64 rows x 64 cols) via float4, zero-pad out-of-range rows
    #pragma unroll
    for (int f = tid; f < 1024; f += 256) {
        int r = f >> 4, c4 = (f & 15) << 2;
        float4 v = make_float4(0.f, 0.f, 0.f, 0.f);
        if (row0 + r < n)
            v = *reinterpret_cast<const float4*>(&X[(size_t)(row0 + r) * HID + c4]);
        sX[r][c4 + 0] = v.x; sX[r][c4 + 1] = v.y;
        sX[r][c4 + 2] = v.z; sX[r][c4 + 3] = v.w;
    }
    __syncthreads();

    const int tr = tid >> 4;   // 0..15 -> rows tr*4..tr*4+3
    const int tc = tid & 15;   // 0..15 -> cols tc*4..tc*4+3
    float acc[4][4];
    #pragma unroll
    for (int i = 0; i < 4; ++i)
        #pragma unroll
        for (int j = 0; j < 4; ++j) acc[i][j] = 0.f;

    #pragma unroll 16
    for (int k = 0; k < 64; ++k) {
        const float4 bv = *reinterpret_cast<const float4*>(&sW[k][tc << 2]);
        float a[4];
        #pragma unroll
        for (int i = 0; i < 4; ++i) a[i] = sX[(tr << 2) + i][k];
        #pragma unroll
        for (int i = 0; i < 4; ++i) {
            acc[i][0] += a[i] * bv.x;
            acc[i][1] += a[i] * bv.y;
            acc[i][2] += a[i] * bv.z;
            acc[i][3] += a[i] * bv.w;
        }
    }

    float4 bb = make_float4(0.f, 0.f, 0.f, 0.f);
    if (ADD_BIAS) bb = *reinterpret_cast<const float4*>(&bias[tc << 2]);
    #pragma unroll
    for (int i = 0; i < 4; ++i) {
        int r = row0 + (tr << 2) + i;
        if (r < n) {
            float s = ROW_SCALE ? dinv[r] : 1.f;
            float4 o;
            o.x = acc[i][0] * s + bb.x;
            o.y = acc[i][1] * s + bb.y;
            o.z = acc[i][2] * s + bb.z;
            o.w = acc[i][3] * s + bb.w;
            *reinterpret_cast<float4*>(&Y[(size_t)r * HID + (tc << 2)]) = o;
        }
    }
}

// ---------------------------------------------------------------------------
// Per-column sum / sum-of-squares for BatchNorm (training-mode batch stats)
// ---------------------------------------------------------------------------
__global__ __launch_bounds__(256) void k_colstats(const float* __restrict__ Y,
                                                  float* __restrict__ outSum,
                                                  float* __restrict__ outSq, int n) {
    const int tid = threadIdx.x;
    const int col = tid & 63, rg = tid >> 6;
    float s = 0.f, q = 0.f;
    for (int r = blockIdx.x * 4 + rg; r < n; r += gridDim.x * 4) {
        float v = Y[(size_t)r * HID + col];
        s += v; q += v * v;
    }
    __shared__ float ls[4][64], lq[4][64];
    ls[rg][col] = s; lq[rg][col] = q;
    __syncthreads();
    if (tid < 64) {
        s = ls[0][tid] + ls[1][tid] + ls[2][tid] + ls[3][tid];
        q = lq[0][tid] + lq[1][tid] + lq[2][tid] + lq[3][tid];
        atomicAdd(&outSum[tid], s);
        atomicAdd(&outSq[tid], q);
    }
}

template <bool RELU>
__global__ __launch_bounds__(256) void k_bnapply(float* __restrict__ Y,
                                                 const float* __restrict__ sum,
                                                 const float* __restrict__ sq,
                                                 const float* __restrict__ g,
                                                 const float* __restrict__ beta, int n) {
    size_t i = (size_t)blockIdx.x * 256 + threadIdx.x;
    if (i >= (size_t)n * HID) return;
    int col = (int)(i & 63);
    float nf = (float)n;
    float m  = sum[col] / nf;
    float v  = sq[col] / nf - m * m;
    float sc = rsqrtf(v + BN_EPS) * g[col];
    float sh = beta[col] - m * sc;
    float y  = Y[i] * sc + sh;
    if (RELU) y = fmaxf(y, 0.f);
    Y[i] = y;
}

// ---------------------------------------------------------------------------
// Degree / dinv / per-graph counts
// ---------------------------------------------------------------------------
__global__ __launch_bounds__(256) void k_deg(const int* __restrict__ dst,
                                             float* __restrict__ deg) {
    int e = blockIdx.x * 256 + threadIdx.x;
    if (e < N_EDGES) atomicAdd(&deg[dst[e]], 1.f);
}
__global__ __launch_bounds__(256) void k_dinv(float* __restrict__ deg) {
    int i = blockIdx.x * 256 + threadIdx.x;
    if (i < N_NODES) deg[i] = rsqrtf(deg[i] + 1.f);
}
__global__ __launch_bounds__(256) void k_counts(const int* __restrict__ batch,
                                                float* __restrict__ cnt) {
    int i = blockIdx.x * 256 + threadIdx.x;
    if (i < N_NODES) atomicAdd(&cnt[batch[i]], 1.f);
}

// ---------------------------------------------------------------------------
// Edge scatter: C[dst] += HW[src]   (HW pre-scaled by dinv[src]); 1 wave/edge row
// ---------------------------------------------------------------------------
__global__ __launch_bounds__(256) void k_scatter(const int* __restrict__ src,
                                                 const int* __restrict__ dst,
                                                 const float* __restrict__ HW,
                                                 float* __restrict__ C) {
    int e = blockIdx.x * 4 + (threadIdx.x >> 6);
    if (e >= N_EDGES) return;
    int lane = threadIdx.x & 63;
    int s = src[e], d = dst[e];
    atomicAdd(&C[(size_t)d * HID + lane], HW[(size_t)s * HID + lane]);
}

// C = (C + HW) * dinv[row] + bias[col] + Hin   (then optional ReLU)
template <bool RELU>
__global__ __launch_bounds__(256) void k_conv_fin(float* __restrict__ C,
                                                  const float* __restrict__ HW,
                                                  const float* __restrict__ Hin,
                                                  const float* __restrict__ dinv,
                                                  const float* __restrict__ bias) {
    size_t i = (size_t)blockIdx.x * 256 + threadIdx.x;
    if (i >= (size_t)N_NODES * HID) return;
    int col = (int)(i & 63);
    int row = (int)(i >> 6);
    float v = (C[i] + HW[i]) * dinv[row] + bias[col] + Hin[i];
    if (RELU) v = fmaxf(v, 0.f);
    C[i] = v;
}

// ---------------------------------------------------------------------------
// Global mean pool (atomics into pooled[G][H])
// ---------------------------------------------------------------------------
__global__ __launch_bounds__(256) void k_pool(const float* __restrict__ Hf,
                                              const int* __restrict__ batch,
                                              float* __restrict__ pooled) {
    int nd = blockIdx.x * 4 + (threadIdx.x >> 6);
    if (nd >= N_NODES) return;
    int lane = threadIdx.x & 63;
    atomicAdd(&pooled[(size_t)batch[nd] * HID + lane], Hf[(size_t)nd * HID + lane]);
}

// ---------------------------------------------------------------------------
// Final head: pooled/count -> relu(W0) -> relu(W1) -> W2 -> out[64,2]
// Single block, 256 threads (tiny).
// ---------------------------------------------------------------------------
__global__ __launch_bounds__(256) void k_final(const float* __restrict__ pooled,
                                               const float* __restrict__ counts,
                                               const float* __restrict__ W0,
                                               const float* __restrict__ b0,
                                               const float* __restrict__ W1,
                                               const float* __restrict__ b1,
                                               const float* __restrict__ W2,
                                               const float* __restrict__ b2,
                                               float* __restrict__ out) {
    __shared__ float P[64][65];
    __shared__ float Z[64][65];
    int tid = threadIdx.x;
    for (int i = tid; i < NGRAPH * HID; i += 256) {
        int r = i >> 6, c = i & 63;
        float cnt = counts[r];
        if (cnt < 1.f) cnt = 1.f;
        P[r][c] = pooled[i] / cnt;
    }
    __syncthreads();
    for (int t = 0; t < 16; ++t) {           // Z = relu(P @ W0 + b0)
        int o = tid + 256 * t; int r = o >> 6, c = o & 63;
        float acc = b0[c];
        #pragma unroll 8
        for (int k = 0; k < 64; ++k) acc += P[r][k] * W0[k * 64 + c];
        Z[r][c] = fmaxf(acc, 0.f);
    }
    __syncthreads();
    for (int t = 0; t < 16; ++t) {           // P = relu(Z @ W1 + b1)
        int o = tid + 256 * t; int r = o >> 6, c = o & 63;
        float acc = b1[c];
        #pragma unroll 8
        for (int k = 0; k < 64; ++k) acc += Z[r][k] * W1[k * 64 + c];
        P[r][c] = fmaxf(acc, 0.f);
    }
    __syncthreads();
    if (tid < NGRAPH * OUTC) {               // out = P @ W2 + b2
        int r = tid >> 1, c = tid & 1;
        float acc = b2[c];
        #pragma unroll 8
        for (int k = 0; k < 64; ++k) acc += P[r][k] * W2[k * OUTC + c];
        out[tid] = acc;
    }
}

// ---------------------------------------------------------------------------
extern "C" void kernel_launch(void* const* d_in, const int* in_sizes, int n_in,
                              void* d_out, int out_size, void* d_ws, size_t ws_size,
                              hipStream_t stream) {
    const float* x        = (const float*)d_in[0];
    const int*   ei       = (const int*)d_in[1];
    const int*   batch    = (const int*)d_in[2];
    const float* pre_W    = (const float*)d_in[3];
    const float* pre_b    = (const float*)d_in[4];
    const float* pre_g    = (const float*)d_in[5];
    const float* pre_beta = (const float*)d_in[6];
    const float* conv_W   = (const float*)d_in[7];
    const float* conv_b   = (const float*)d_in[8];
    const float* post_W   = (const float*)d_in[9];
    const float* post_b   = (const float*)d_in[10];
    const float* post_g   = (const float*)d_in[11];
    const float* post_beta= (const float*)d_in[12];
    const float* fW0 = (const float*)d_in[13];
    const float* fb0 = (const float*)d_in[14];
    const float* fW1 = (const float*)d_in[15];
    const float* fb1 = (const float*)d_in[16];
    const float* fW2 = (const float*)d_in[17];
    const float* fb2 = (const float*)d_in[18];
    float* out = (float*)d_out;

    const size_t NH = (size_t)N_NODES * HID;
    float* ws     = (float*)d_ws;
    float* A      = ws;
    float* B      = A + NH;
    float* C      = B + NH;
    float* deg    = C + NH;                 // N_NODES (becomes dinv in place)
    float* stats  = deg + N_NODES;          // 6*64 sums, then 6*64 sumsqs
    float* pooled = stats + 768;            // 64*64
    float* cnt    = pooled + NGRAPH * HID;  // 64
    // zero all accumulators in one contiguous memset (deg..cnt)
    size_t zeroFloats = (size_t)N_NODES + 768 + NGRAPH * HID + NGRAPH;
    hipMemsetAsync(deg, 0, zeroFloats * sizeof(float), stream);

    const int* srcp = ei;
    const int* dstp = ei + N_EDGES;

    const int gGemm  = (N_NODES + 63) / 64;        // 1563
    const int gElem  = (int)((NH + 255) / 256);    // 25000
    const int gEdge  = (N_EDGES + 255) / 256;
    const int gEdge4 = (N_EDGES + 3) / 4;
    const int gNode  = (N_NODES + 255) / 256;
    const int gNode4 = (N_NODES + 3) / 4;

    k_deg<<<gEdge, 256, 0, stream>>>(dstp, deg);
    k_counts<<<gNode, 256, 0, stream>>>(batch, cnt);
    k_dinv<<<gNode, 256, 0, stream>>>(deg);        // deg -> dinv in place

    // ---- pre-processing: Linear -> BN (ReLU except last) ----
    const float* h = x;
    for (int i = 0; i < 3; ++i) {
        float* y = (i & 1) ? B : A;                // A, B, A
        k_gemm<true, false><<<gGemm, 256, 0, stream>>>(h, pre_W + i * 4096,
                                                       pre_b + i * 64, nullptr, y, N_NODES);
        float* sum = stats + i * 64;
        float* sq  = stats + 384 + i * 64;
        k_colstats<<<1024, 256, 0, stream>>>(y, sum, sq, N_NODES);
        if (i != 2)
            k_bnapply<true><<<gElem, 256, 0, stream>>>(y, sum, sq, pre_g + i * 64,
                                                       pre_beta + i * 64, N_NODES);
        else
            k_bnapply<false><<<gElem, 256, 0, stream>>>(y, sum, sq, pre_g + i * 64,
                                                        pre_beta + i * 64, N_NODES);
        h = y;
    }
    // h == A

    // ---- GCNConv stack with residual (ReLU except last) ----
    float* hw = B;
    for (int i = 0; i < 6; ++i) {
        float* in   = (i & 1) ? C : A;
        float* outb = (i & 1) ? A : C;
        // hw = (in @ W) * dinv[row]   (no bias)
        k_gemm<false, true><<<gGemm, 256, 0, stream>>>(in, conv_W + i * 4096,
                                                       nullptr, deg, hw, N_NODES);
        hipMemsetAsync(outb, 0, NH * sizeof(float), stream);
        k_scatter<<<gEdge4, 256, 0, stream>>>(srcp, dstp, hw, outb);
        if (i != 5)
            k_conv_fin<true><<<gElem, 256, 0, stream>>>(outb, hw, in, deg, conv_b + i * 64);
        else
            k_conv_fin<false><<<gElem, 256, 0, stream>>>(outb, hw, in, deg, conv_b + i * 64);
    }
    // conv output in A (i=5 wrote outb=A)

    // ---- post-processing: Linear -> BN (ReLU except last) ----
    h = A;
    for (int i = 0; i < 3; ++i) {
        float* y = (i & 1) ? C : B;                // B, C, B
        k_gemm<true, false><<<gGemm, 256, 0, stream>>>(h, post_W + i * 4096,
                                                       post_b + i * 64, nullptr, y, N_NODES);
        float* sum = stats + (3 + i) * 64;
        float* sq  = stats + 384 + (3 + i) * 64;
        k_colstats<<<1024, 256, 0, stream>>>(y, sum, sq, N_NODES);
        if (i != 2)
            k_bnapply<true><<<gElem, 256, 0, stream>>>(y, sum, sq, post_g + i * 64,
                                                       post_beta + i * 64, N_NODES);
        else
            k_bnapply<false><<<gElem, 256, 0, stream>>>(y, sum, sq, post_g + i * 64,
                                                        post_beta + i * 64, N_NODES);
        h = y;
    }
    // h == B

    // ---- pool + head ----
    k_pool<<<gNode4, 256, 0, stream>>>(h, batch, pooled);
    k_final<<<1, 256, 0, stream>>>(pooled, cnt, fW0, fb0, fW1, fb1, fW2, fb2, out);
}

// Round 2
// 1190.707 us; speedup vs baseline: 1.8912x; 1.8912x over previous
//
#include <hip/hip_runtime.h>

#define N_NODES 100000
#define N_EDGES 800000
#define HID 64
#define NGRAPH 64
#define OUTC 2
#define BN_EPS 1e-5f
#define NSTAT_BLK 256
#define NSCAN_BLK ((N_NODES + 255) / 256)   // 391

// ---------------------------------------------------------------------------
// GEMM: Y[n,64] = T(X)[n,64] @ W[64,64] (+bias) (opt row-scale by dinv)
// T(X) = optional per-column BN (scale/shift) + optional ReLU, fused on load.
// IN_MODE: 0 = identity, 1 = BN, 2 = BN + ReLU
// ---------------------------------------------------------------------------
template <int IN_MODE, bool ADD_BIAS, bool ROW_SCALE>
__global__ __launch_bounds__(256) void k_gemm(const float* __restrict__ X,
                                              const float* __restrict__ W,
                                              const float* __restrict__ bias,
                                              const float* __restrict__ dinv,
                                              const float* __restrict__ scsh,
                                              float* __restrict__ Y, int n) {
    __shared__ float sW[64][64];
    __shared__ float sX[64][66];
    const int tid  = threadIdx.x;
    const int row0 = blockIdx.x * 64;

    {   // load W (4096 floats) via float4
        const float4* Wv  = reinterpret_cast<const float4*>(W);
        float4*       sWv = reinterpret_cast<float4*>(&sW[0][0]);
        #pragma unroll
        for (int i = tid; i < 1024; i += 256) sWv[i] = Wv[i];
    }
    // load X tile (64x64) via float4 with fused BN/ReLU transform
    #pragma unroll
    for (int f = tid; f < 1024; f += 256) {
        int r = f >> 4, c4 = (f & 15) << 2;
        float4 v = make_float4(0.f, 0.f, 0.f, 0.f);
        if (row0 + r < n)
            v = *reinterpret_cast<const float4*>(&X[(size_t)(row0 + r) * HID + c4]);
        if (IN_MODE >= 1) {
            float4 sc = *reinterpret_cast<const float4*>(&scsh[c4]);
            float4 sh = *reinterpret_cast<const float4*>(&scsh[64 + c4]);
            v.x = v.x * sc.x + sh.x; v.y = v.y * sc.y + sh.y;
            v.z = v.z * sc.z + sh.z; v.w = v.w * sc.w + sh.w;
            if (IN_MODE == 2) {
                v.x = fmaxf(v.x, 0.f); v.y = fmaxf(v.y, 0.f);
                v.z = fmaxf(v.z, 0.f); v.w = fmaxf(v.w, 0.f);
            }
        }
        sX[r][c4 + 0] = v.x; sX[r][c4 + 1] = v.y;
        sX[r][c4 + 2] = v.z; sX[r][c4 + 3] = v.w;
    }
    __syncthreads();

    const int tr = tid >> 4;
    const int tc = tid & 15;
    float acc[4][4];
    #pragma unroll
    for (int i = 0; i < 4; ++i)
        #pragma unroll
        for (int j = 0; j < 4; ++j) acc[i][j] = 0.f;

    #pragma unroll 16
    for (int k = 0; k < 64; ++k) {
        const float4 bv = *reinterpret_cast<const float4*>(&sW[k][tc << 2]);
        float a[4];
        #pragma unroll
        for (int i = 0; i < 4; ++i) a[i] = sX[(tr << 2) + i][k];
        #pragma unroll
        for (int i = 0; i < 4; ++i) {
            acc[i][0] += a[i] * bv.x;
            acc[i][1] += a[i] * bv.y;
            acc[i][2] += a[i] * bv.z;
            acc[i][3] += a[i] * bv.w;
        }
    }

    float4 bb = make_float4(0.f, 0.f, 0.f, 0.f);
    if (ADD_BIAS) bb = *reinterpret_cast<const float4*>(&bias[tc << 2]);
    #pragma unroll
    for (int i = 0; i < 4; ++i) {
        int r = row0 + (tr << 2) + i;
        if (r < n) {
            float s = ROW_SCALE ? dinv[r] : 1.f;
            float4 o;
            o.x = acc[i][0] * s + bb.x;
            o.y = acc[i][1] * s + bb.y;
            o.z = acc[i][2] * s + bb.z;
            o.w = acc[i][3] * s + bb.w;
            *reinterpret_cast<float4*>(&Y[(size_t)r * HID + (tc << 2)]) = o;
        }
    }
}

// ---------------------------------------------------------------------------
// BN column stats: deterministic per-block partials (no atomics)
// ---------------------------------------------------------------------------
__global__ __launch_bounds__(256) void k_colstats(const float* __restrict__ Y,
                                                  float* __restrict__ partial, int n) {
    const int tid = threadIdx.x;
    const int col = tid & 63, rg = tid >> 6;
    float s = 0.f, q = 0.f;
    for (int r = blockIdx.x * 4 + rg; r < n; r += NSTAT_BLK * 4) {
        float v = Y[(size_t)r * HID + col];
        s += v; q += v * v;
    }
    __shared__ float ls[4][64], lq[4][64];
    ls[rg][col] = s; lq[rg][col] = q;
    __syncthreads();
    if (tid < 64) {
        s = ls[0][tid] + ls[1][tid] + ls[2][tid] + ls[3][tid];
        q = lq[0][tid] + lq[1][tid] + lq[2][tid] + lq[3][tid];
        partial[blockIdx.x * 128 + tid]      = s;
        partial[blockIdx.x * 128 + 64 + tid] = q;
    }
}

// Reduce partials -> scale/shift for this BN layer
__global__ __launch_bounds__(64) void k_statsfin(const float* __restrict__ partial,
                                                 const float* __restrict__ g,
                                                 const float* __restrict__ beta,
                                                 float* __restrict__ scsh, int n) {
    int c = threadIdx.x;
    float S = 0.f, Q = 0.f;
    for (int b = 0; b < NSTAT_BLK; ++b) {
        S += partial[b * 128 + c];
        Q += partial[b * 128 + 64 + c];
    }
    float nf = (float)n;
    float m  = S / nf;
    float v  = Q / nf - m * m;
    float sc = rsqrtf(v + BN_EPS) * g[c];
    scsh[c]      = sc;
    scsh[64 + c] = beta[c] - m * sc;
}

// ---------------------------------------------------------------------------
// CSR build: degree, exclusive scan, fill (atomicSub countdown into indeg)
// ---------------------------------------------------------------------------
__global__ __launch_bounds__(256) void k_deg(const int* __restrict__ dst,
                                             int* __restrict__ indeg) {
    int e = blockIdx.x * 256 + threadIdx.x;
    if (e < N_EDGES) atomicAdd(&indeg[dst[e]], 1);
}

__global__ __launch_bounds__(256) void k_scanpart(const int* __restrict__ indeg,
                                                  int* __restrict__ bsum) {
    __shared__ int s[256];
    int i = blockIdx.x * 256 + threadIdx.x;
    s[threadIdx.x] = (i < N_NODES) ? indeg[i] : 0;
    __syncthreads();
    for (int off = 128; off > 0; off >>= 1) {
        if (threadIdx.x < off) s[threadIdx.x] += s[threadIdx.x + off];
        __syncthreads();
    }
    if (threadIdx.x == 0) bsum[blockIdx.x] = s[0];
}

__global__ __launch_bounds__(512) void k_scanmid(int* __restrict__ bsum, int nblk) {
    __shared__ int s[512];
    int t = threadIdx.x;
    int v = (t < nblk) ? bsum[t] : 0;
    s[t] = v;
    __syncthreads();
    for (int off = 1; off < 512; off <<= 1) {
        int x = (t >= off) ? s[t - off] : 0;
        __syncthreads();
        s[t] += x;
        __syncthreads();
    }
    if (t < nblk) bsum[t] = s[t] - v;   // exclusive
}

__global__ __launch_bounds__(256) void k_scanfinal(const int* __restrict__ indeg,
                                                   const int* __restrict__ bsum,
                                                   int* __restrict__ rowptr) {
    __shared__ int s[256];
    int t = threadIdx.x;
    int i = blockIdx.x * 256 + t;
    int v = (i < N_NODES) ? indeg[i] : 0;
    s[t] = v;
    __syncthreads();
    for (int off = 1; off < 256; off <<= 1) {
        int x = (t >= off) ? s[t - off] : 0;
        __syncthreads();
        s[t] += x;
        __syncthreads();
    }
    if (i < N_NODES) rowptr[i] = bsum[blockIdx.x] + s[t] - v;
    if (i == 0) rowptr[N_NODES] = N_EDGES;
}

__global__ __launch_bounds__(256) void k_dinv(const int* __restrict__ indeg,
                                              float* __restrict__ dinv) {
    int i = blockIdx.x * 256 + threadIdx.x;
    if (i < N_NODES) dinv[i] = rsqrtf((float)indeg[i] + 1.f);
}

// fill: consumes indeg as a countdown cursor (indeg ends at 0)
__global__ __launch_bounds__(256) void k_fill(const int* __restrict__ src,
                                              const int* __restrict__ dst,
                                              const int* __restrict__ rowptr,
                                              int* __restrict__ indeg,
                                              int* __restrict__ colidx) {
    int e = blockIdx.x * 256 + threadIdx.x;
    if (e >= N_EDGES) return;
    int d = dst[e];
    int pos = rowptr[d] + (atomicSub(&indeg[d], 1) - 1);
    colidx[pos] = src[e];
}

// ---------------------------------------------------------------------------
// Fused gather + conv finalize: one wave per dst node.
// Out[d] = (sum_{s in N(d)} HW[s] + HW[d]) * dinv[d] + bias + T(Hin[d]), opt ReLU
// IN_MODE: 0 = identity residual, 1 = BN-transform residual
// ---------------------------------------------------------------------------
template <int IN_MODE, bool RELU>
__global__ __launch_bounds__(256) void k_gather(const int* __restrict__ rowptr,
                                                const int* __restrict__ colidx,
                                                const float* __restrict__ HW,
                                                const float* __restrict__ Hin,
                                                const float* __restrict__ dinv,
                                                const float* __restrict__ bias,
                                                const float* __restrict__ scsh,
                                                float* __restrict__ Out) {
    int d = blockIdx.x * 4 + (threadIdx.x >> 6);
    if (d >= N_NODES) return;
    int lane = threadIdx.x & 63;
    int j0 = rowptr[d], j1 = rowptr[d + 1];
    float acc = HW[(size_t)d * HID + lane];          // self-loop term
    for (int j = j0; j < j1; ++j) {
        int s = colidx[j];
        acc += HW[(size_t)s * HID + lane];
    }
    float hin = Hin[(size_t)d * HID + lane];
    if (IN_MODE == 1) hin = hin * scsh[lane] + scsh[64 + lane];
    float v = acc * dinv[d] + bias[lane] + hin;
    if (RELU) v = fmaxf(v, 0.f);
    Out[(size_t)d * HID + lane] = v;
}

// ---------------------------------------------------------------------------
// Segment pool over sorted batch (no atomics) + fused final BN
// ---------------------------------------------------------------------------
__device__ __forceinline__ int lowerb(const int* __restrict__ b, int n, int v) {
    int lo = 0, hi = n;
    while (lo < hi) { int m = (lo + hi) >> 1; if (b[m] < v) lo = m + 1; else hi = m; }
    return lo;
}

__global__ __launch_bounds__(256) void k_pool(const float* __restrict__ Y,
                                              const int* __restrict__ batch,
                                              const float* __restrict__ scsh,
                                              float* __restrict__ pooled) {
    int gidx = blockIdx.x;
    int tid = threadIdx.x, col = tid & 63, rg = tid >> 6;
    int lo = lowerb(batch, N_NODES, gidx);
    int hi = lowerb(batch, N_NODES, gidx + 1);
    float s = 0.f;
    for (int r = lo + rg; r < hi; r += 4) s += Y[(size_t)r * HID + col];
    __shared__ float ls[4][64];
    ls[rg][col] = s;
    __syncthreads();
    if (tid < 64) {
        int cnt = hi - lo;
        float out = 0.f;
        if (cnt > 0) {
            float mean = (ls[0][tid] + ls[1][tid] + ls[2][tid] + ls[3][tid]) / (float)cnt;
            out = mean * scsh[tid] + scsh[64 + tid];
        }
        pooled[gidx * 64 + tid] = out;
    }
}

// ---------------------------------------------------------------------------
// Final head: pooled(already mean+BN) -> relu(W0) -> relu(W1) -> W2 -> out
// ---------------------------------------------------------------------------
__global__ __launch_bounds__(256) void k_final(const float* __restrict__ pooled,
                                               const float* __restrict__ W0,
                                               const float* __restrict__ b0,
                                               const float* __restrict__ W1,
                                               const float* __restrict__ b1,
                                               const float* __restrict__ W2,
                                               const float* __restrict__ b2,
                                               float* __restrict__ out) {
    __shared__ float P[64][65];
    __shared__ float Z[64][65];
    int tid = threadIdx.x;
    for (int i = tid; i < NGRAPH * HID; i += 256) P[i >> 6][i & 63] = pooled[i];
    __syncthreads();
    for (int t = 0; t < 16; ++t) {
        int o = tid + 256 * t; int r = o >> 6, c = o & 63;
        float acc = b0[c];
        #pragma unroll 8
        for (int k = 0; k < 64; ++k) acc += P[r][k] * W0[k * 64 + c];
        Z[r][c] = fmaxf(acc, 0.f);
    }
    __syncthreads();
    for (int t = 0; t < 16; ++t) {
        int o = tid + 256 * t; int r = o >> 6, c = o & 63;
        float acc = b1[c];
        #pragma unroll 8
        for (int k = 0; k < 64; ++k) acc += Z[r][k] * W1[k * 64 + c];
        P[r][c] = fmaxf(acc, 0.f);
    }
    __syncthreads();
    if (tid < NGRAPH * OUTC) {
        int r = tid >> 1, c = tid & 1;
        float acc = b2[c];
        #pragma unroll 8
        for (int k = 0; k < 64; ++k) acc += P[r][k] * W2[k * OUTC + c];
        out[tid] = acc;
    }
}

// ---------------------------------------------------------------------------
extern "C" void kernel_launch(void* const* d_in, const int* in_sizes, int n_in,
                              void* d_out, int out_size, void* d_ws, size_t ws_size,
                              hipStream_t stream) {
    const float* x        = (const float*)d_in[0];
    const int*   ei       = (const int*)d_in[1];
    const int*   batch    = (const int*)d_in[2];
    const float* pre_W    = (const float*)d_in[3];
    const float* pre_b    = (const float*)d_in[4];
    const float* pre_g    = (const float*)d_in[5];
    const float* pre_beta = (const float*)d_in[6];
    const float* conv_W   = (const float*)d_in[7];
    const float* conv_b   = (const float*)d_in[8];
    const float* post_W   = (const float*)d_in[9];
    const float* post_b   = (const float*)d_in[10];
    const float* post_g   = (const float*)d_in[11];
    const float* post_beta= (const float*)d_in[12];
    const float* fW0 = (const float*)d_in[13];
    const float* fb0 = (const float*)d_in[14];
    const float* fW1 = (const float*)d_in[15];
    const float* fb1 = (const float*)d_in[16];
    const float* fW2 = (const float*)d_in[17];
    const float* fb2 = (const float*)d_in[18];
    float* out = (float*)d_out;

    const size_t NH = (size_t)N_NODES * HID;
    float* ws      = (float*)d_ws;
    float* A       = ws;
    float* B       = A + NH;
    float* C       = B + NH;
    float* dinv    = C + NH;                    // N
    float* partial = dinv + N_NODES;            // 256*128
    float* scsh    = partial + NSTAT_BLK * 128; // 6 slots of 128
    float* pooled  = scsh + 6 * 128;            // 64*64
    int*   indeg   = (int*)(pooled + NGRAPH * HID);  // N (countdown-consumed)
    int*   rowptr  = indeg + N_NODES;           // N+1
    int*   colidx  = rowptr + N_NODES + 1;      // E
    int*   bsum    = colidx + N_EDGES;          // NSCAN_BLK

    const int* srcp = ei;
    const int* dstp = ei + N_EDGES;

    const int gGemm  = (N_NODES + 63) / 64;
    const int gEdge  = (N_EDGES + 255) / 256;
    const int gNode  = (N_NODES + 255) / 256;
    const int gNode4 = (N_NODES + 3) / 4;

    // ---- CSR build ----
    hipMemsetAsync(indeg, 0, N_NODES * sizeof(int), stream);
    k_deg<<<gEdge, 256, 0, stream>>>(dstp, indeg);
    k_scanpart<<<NSCAN_BLK, 256, 0, stream>>>(indeg, bsum);
    k_scanmid<<<1, 512, 0, stream>>>(bsum, NSCAN_BLK);
    k_scanfinal<<<NSCAN_BLK, 256, 0, stream>>>(indeg, bsum, rowptr);
    k_dinv<<<gNode, 256, 0, stream>>>(indeg, dinv);
    k_fill<<<gEdge, 256, 0, stream>>>(srcp, dstp, rowptr, indeg, colidx);

    // ---- pre-processing: GEMM(+fused prev BN/ReLU) -> stats ----
    // pre0: x -> A ; pre1: T0(A) -> B ; pre2: T1(B) -> A
    k_gemm<0, true, false><<<gGemm, 256, 0, stream>>>(x, pre_W, pre_b, nullptr, nullptr, A, N_NODES);
    k_colstats<<<NSTAT_BLK, 256, 0, stream>>>(A, partial, N_NODES);
    k_statsfin<<<1, 64, 0, stream>>>(partial, pre_g, pre_beta, scsh + 0 * 128, N_NODES);

    k_gemm<2, true, false><<<gGemm, 256, 0, stream>>>(A, pre_W + 4096, pre_b + 64, nullptr, scsh + 0 * 128, B, N_NODES);
    k_colstats<<<NSTAT_BLK, 256, 0, stream>>>(B, partial, N_NODES);
    k_statsfin<<<1, 64, 0, stream>>>(partial, pre_g + 64, pre_beta + 64, scsh + 1 * 128, N_NODES);

    k_gemm<2, true, false><<<gGemm, 256, 0, stream>>>(B, pre_W + 2 * 4096, pre_b + 128, nullptr, scsh + 1 * 128, A, N_NODES);
    k_colstats<<<NSTAT_BLK, 256, 0, stream>>>(A, partial, N_NODES);
    k_statsfin<<<1, 64, 0, stream>>>(partial, pre_g + 128, pre_beta + 128, scsh + 2 * 128, N_NODES);

    // ---- GCNConv stack: GEMM(row-scale, fused BN for conv0) + gather-finalize
    // conv_i: in (A/C alternating) -> HW=B -> out (C/A alternating)
    for (int i = 0; i < 6; ++i) {
        const float* in = (i & 1) ? C : A;
        float*      outb = (i & 1) ? A : C;
        const float* Wl = conv_W + i * 4096;
        const float* bl = conv_b + i * 64;
        if (i == 0)
            k_gemm<1, false, true><<<gGemm, 256, 0, stream>>>(in, Wl, nullptr, dinv, scsh + 2 * 128, B, N_NODES);
        else
            k_gemm<0, false, true><<<gGemm, 256, 0, stream>>>(in, Wl, nullptr, dinv, nullptr, B, N_NODES);

        if (i == 0)
            k_gather<1, true ><<<gNode4, 256, 0, stream>>>(rowptr, colidx, B, in, dinv, bl, scsh + 2 * 128, outb);
        else if (i != 5)
            k_gather<0, true ><<<gNode4, 256, 0, stream>>>(rowptr, colidx, B, in, dinv, bl, nullptr, outb);
        else
            k_gather<0, false><<<gNode4, 256, 0, stream>>>(rowptr, colidx, B, in, dinv, bl, nullptr, outb);
    }
    // conv output in A

    // ---- post-processing ----
    // post0: A -> B ; post1: T3(B) -> C ; post2: T4(C) -> B
    k_gemm<0, true, false><<<gGemm, 256, 0, stream>>>(A, post_W, post_b, nullptr, nullptr, B, N_NODES);
    k_colstats<<<NSTAT_BLK, 256, 0, stream>>>(B, partial, N_NODES);
    k_statsfin<<<1, 64, 0, stream>>>(partial, post_g, post_beta, scsh + 3 * 128, N_NODES);

    k_gemm<2, true, false><<<gGemm, 256, 0, stream>>>(B, post_W + 4096, post_b + 64, nullptr, scsh + 3 * 128, C, N_NODES);
    k_colstats<<<NSTAT_BLK, 256, 0, stream>>>(C, partial, N_NODES);
    k_statsfin<<<1, 64, 0, stream>>>(partial, post_g + 64, post_beta + 64, scsh + 4 * 128, N_NODES);

    k_gemm<2, true, false><<<gGemm, 256, 0, stream>>>(C, post_W + 2 * 4096, post_b + 128, nullptr, scsh + 4 * 128, B, N_NODES);
    k_colstats<<<NSTAT_BLK, 256, 0, stream>>>(B, partial, N_NODES);
    k_statsfin<<<1, 64, 0, stream>>>(partial, post_g + 128, post_beta + 128, scsh + 5 * 128, N_NODES);

    // ---- pool (segment reduce, fused final BN) + head ----
    k_pool<<<NGRAPH, 256, 0, stream>>>(B, batch, scsh + 5 * 128, pooled);
    k_final<<<1, 256, 0, stream>>>(pooled, fW0, fb0, fW1, fb1, fW2, fb2, out);
}